// Round 3
// baseline (360.021 us; speedup 1.0000x reference)
//
#include <hip/hip_runtime.h>
#include <math.h>

#define NCLS 80
#define BINS 16
#define BATCH 32
#define MAX_GT 32
#define NA 8400
#define NT 2100          // threads per batch = 8400/4 anchors each
#define ALPHA_C 0.25f
#define W_CLS 1.0
#define W_IOU 7.5
#define W_DFL 1.5
#define EPS_F 1e-7f

// acc layout (doubles): [0]=cls_sum [1]=iou_sum [2]=dfl_sum [3]=pos_count
__global__ __launch_bounds__(64) void yolo_loss_main(
    const float* __restrict__ p0, const float* __restrict__ p1, const float* __restrict__ p2,
    const float* __restrict__ gt_bboxes, const int* __restrict__ gt_labels,
    const int* __restrict__ matched, double* __restrict__ acc)
{
    const int t = blockIdx.x * 64 + threadIdx.x;   // thread id within batch, 4 anchors each
    const int b = blockIdx.y;

    float cls_acc = 0.f, iou_acc = 0.f, dfl_acc = 0.f;
    int pos_cnt = 0;

    if (t < NT) {
        const float* p; int HW, W, off, gbase; float stride;
        if (t < 1600)      { p = p0; HW = 6400; W = 80; stride = 8.f;  off = t * 4;          gbase = 0;    }
        else if (t < 2000) { p = p1; HW = 1600; W = 40; stride = 16.f; off = (t - 1600) * 4; gbase = 6400; }
        else               { p = p2; HW = 400;  W = 20; stride = 32.f; off = (t - 2000) * 4; gbase = 8000; }

        // all 4 anchors share the same row h (off%4==0 and W%4==0)
        const int h  = off / W;
        const int w0 = off - h * W;
        const float cy = ((float)h + 0.5f) * stride;
        float cx[4];
        #pragma unroll
        for (int j = 0; j < 4; ++j) cx[j] = ((float)(w0 + j) + 0.5f) * stride;

        const float* pb = p + ((size_t)b * 144) * (size_t)HW + (size_t)off;

        const int4 m4 = *(const int4*)(matched + (size_t)b * NA + gbase + off);
        const int mm[4] = {m4.x, m4.y, m4.z, m4.w};

        bool  pos[4]; int lbl[4];
        float tx1[4], ty1[4], tx2[4], ty2[4];
        float td[4][4];                 // [anchor][side] target dist in bin units

        #pragma unroll
        for (int j = 0; j < 4; ++j) {
            pos[j] = (mm[j] >= 0);
            int idx = pos[j] ? mm[j] : 0;
            lbl[j] = gt_labels[b * MAX_GT + idx];
            float4 tb = *(const float4*)(gt_bboxes + ((size_t)b * MAX_GT + idx) * 4);
            tx1[j] = tb.x; ty1[j] = tb.y; tx2[j] = tb.z; ty2[j] = tb.w;
            float inv_s = 1.f / stride;
            td[j][0] = fmaxf(cx[j] - tb.x, 0.f) * inv_s;
            td[j][1] = fmaxf(cy    - tb.y, 0.f) * inv_s;
            td[j][2] = fmaxf(tb.z - cx[j], 0.f) * inv_s;
            td[j][3] = fmaxf(tb.w - cy,    0.f) * inv_s;
        }

        float pdist[4][4];              // [anchor][side] predicted dist (pixels)
        float dflj[4] = {0.f, 0.f, 0.f, 0.f};

        #pragma unroll
        for (int k = 0; k < 4; ++k) {
            const float* pc = pb + (size_t)(k * BINS) * HW;
            float v[BINS][4];
            #pragma unroll
            for (int i = 0; i < BINS; ++i) {
                float4 q = *(const float4*)(pc + (size_t)i * HW);
                v[i][0] = q.x; v[i][1] = q.y; v[i][2] = q.z; v[i][3] = q.w;
            }
            #pragma unroll
            for (int j = 0; j < 4; ++j) {
                float tval = fminf(td[j][k], (float)(BINS - 1) - 1e-6f);
                int   lo = (int)floorf(tval);          // 0..14 -> hi = lo+1 <= 15 always
                float fr = tval - (float)lo;

                float mx = v[0][j];
                #pragma unroll
                for (int i = 1; i < BINS; ++i) mx = fmaxf(mx, v[i][j]);

                float se = 0.f, we = 0.f, vlo = 0.f, vhi = 0.f;
                #pragma unroll
                for (int i = 0; i < BINS; ++i) {
                    float e = __expf(v[i][j] - mx);
                    se += e;
                    we += (float)i * e;
                    vlo = (i == lo)     ? v[i][j] : vlo;
                    vhi = (i == lo + 1) ? v[i][j] : vhi;
                }
                pdist[j][k] = (we / se) * stride;
                float lse = mx + __logf(se);
                if (pos[j]) dflj[j] += -((1.f - fr) * (vlo - lse) + fr * (vhi - lse));
            }
        }

        // focal-BCE classification over 80 classes, all 4 anchors
        const float* pcls = pb + (size_t)(4 * BINS) * HW;
        #pragma unroll 8
        for (int c = 0; c < NCLS; ++c) {
            float4 q = *(const float4*)(pcls + (size_t)c * HW);
            float s4[4] = {q.x, q.y, q.z, q.w};
            #pragma unroll
            for (int j = 0; j < 4; ++j) {
                float s  = s4[j];
                float tt = (pos[j] && c == lbl[j]) ? 1.f : 0.f;
                float e   = __expf(-fabsf(s));
                float inv = 1.f / (1.f + e);
                float prob = (s >= 0.f) ? inv : e * inv;   // sigmoid(s)
                float ce  = fmaxf(s, 0.f) - s * tt + __logf(1.f + e);
                float p_t = prob * tt + (1.f - prob) * (1.f - tt);
                float alpha_t = tt * ALPHA_C + (1.f - tt) * (1.f - ALPHA_C);
                float om = 1.f - p_t;
                cls_acc += alpha_t * om * om * ce;
            }
        }

        #pragma unroll
        for (int j = 0; j < 4; ++j) {
            if (pos[j]) {
                float px1 = cx[j] - pdist[j][0], py1 = cy - pdist[j][1];
                float px2 = cx[j] + pdist[j][2], py2 = cy + pdist[j][3];
                float ix1 = fmaxf(px1, tx1[j]), iy1 = fmaxf(py1, ty1[j]);
                float ix2 = fminf(px2, tx2[j]), iy2 = fminf(py2, ty2[j]);
                float inter  = fmaxf(ix2 - ix1, 0.f) * fmaxf(iy2 - iy1, 0.f);
                float area_p = fmaxf(px2 - px1, 0.f) * fmaxf(py2 - py1, 0.f);
                float area_t = fmaxf(tx2[j] - tx1[j], 0.f) * fmaxf(ty2[j] - ty1[j], 0.f);
                float iou = inter / (area_p + area_t - inter + EPS_F);
                iou_acc += 1.f - iou;
                dfl_acc += dflj[j];
                pos_cnt += 1;
            }
        }
    }

    // single-wave block: 64-lane shuffle reduction, one atomic set per block
    #pragma unroll
    for (int o = 32; o > 0; o >>= 1) {
        cls_acc += __shfl_down(cls_acc, o);
        iou_acc += __shfl_down(iou_acc, o);
        dfl_acc += __shfl_down(dfl_acc, o);
        pos_cnt += __shfl_down(pos_cnt, o);
    }
    if (threadIdx.x == 0) {
        atomicAdd(&acc[0], (double)cls_acc);
        atomicAdd(&acc[1], (double)iou_acc);
        atomicAdd(&acc[2], (double)dfl_acc);
        atomicAdd(&acc[3], (double)pos_cnt);
    }
}

__global__ void yolo_loss_finalize(const double* __restrict__ acc, float* __restrict__ out)
{
    double np = acc[3] < 1.0 ? 1.0 : acc[3];
    double total = W_CLS * acc[0] / np + W_IOU * acc[1] / np + W_DFL * acc[2] / (np * 4.0);
    out[0] = (float)total;
}

extern "C" void kernel_launch(void* const* d_in, const int* in_sizes, int n_in,
                              void* d_out, int out_size, void* d_ws, size_t ws_size,
                              hipStream_t stream)
{
    const float* p0        = (const float*)d_in[0];
    const float* p1        = (const float*)d_in[1];
    const float* p2        = (const float*)d_in[2];
    const float* gt_bboxes = (const float*)d_in[3];
    const int*   gt_labels = (const int*)d_in[4];
    const int*   matched   = (const int*)d_in[5];
    float*  out = (float*)d_out;
    double* acc = (double*)d_ws;

    (void)hipMemsetAsync(acc, 0, 4 * sizeof(double), stream);

    dim3 grid((NT + 63) / 64, BATCH);   // 33 x 32 blocks, 1 wave each
    yolo_loss_main<<<grid, 64, 0, stream>>>(p0, p1, p2, gt_bboxes, gt_labels, matched, acc);
    yolo_loss_finalize<<<1, 1, 0, stream>>>(acc, out);
}

// Round 4
// 226.303 us; speedup vs baseline: 1.5909x; 1.5909x over previous
//
#include <hip/hip_runtime.h>
#include <math.h>

#define NCLS 80
#define BINS 16
#define BATCH 32
#define MAX_GT 32
#define NA 8400
#define AN (BATCH * NA)       // 268800 anchors total
#define NT 2100               // anchor-quads per batch image
#define ALPHA_C 0.25f
#define W_CLS 1.0
#define W_IOU 7.5
#define W_DFL 1.5
#define EPS_F 1e-7f

// acc layout (doubles): [0]=cls_sum [1]=iou_sum [2]=dfl_sum [3]=pos_count

__device__ __forceinline__ void scale_map(int t,
    const float* __restrict__ p0, const float* __restrict__ p1, const float* __restrict__ p2,
    const float*& p, int& HW, int& W, float& stride, int& off, int& gbase)
{
    if (t < 1600)      { p = p0; HW = 6400; W = 80; stride = 8.f;  off = t * 4;          gbase = 0;    }
    else if (t < 2000) { p = p1; HW = 1600; W = 40; stride = 16.f; off = (t - 1600) * 4; gbase = 6400; }
    else               { p = p2; HW = 400;  W = 20; stride = 32.f; off = (t - 2000) * 4; gbase = 8000; }
}

// block = 256 threads (4 waves). One atomic per call. Safe for repeated calls.
__device__ __forceinline__ void block_reduce_atomic(float val, double* __restrict__ target)
{
    __shared__ float s[4];
    __syncthreads();                       // protect s[] from a previous call
    #pragma unroll
    for (int o = 32; o > 0; o >>= 1) val += __shfl_down(val, o);
    const int wave = threadIdx.x >> 6, lane = threadIdx.x & 63;
    if (lane == 0) s[wave] = val;
    __syncthreads();
    if (threadIdx.x == 0) atomicAdd(target, (double)(s[0] + s[1] + s[2] + s[3]));
}

// grid (9, 8, BATCH), block 256.  role = blockIdx.y: 0..3 -> DFL side k, 4..7 -> cls slice
__global__ __launch_bounds__(256) void yolo_dfl_cls(
    const float* __restrict__ p0, const float* __restrict__ p1, const float* __restrict__ p2,
    const float* __restrict__ gt_bboxes, const int* __restrict__ gt_labels,
    const int* __restrict__ matched, float* __restrict__ pdist, double* __restrict__ acc)
{
    const int t    = blockIdx.x * 256 + threadIdx.x;   // anchor-quad id within batch
    const int role = blockIdx.y;
    const int b    = blockIdx.z;

    float part = 0.f;

    if (role >= 4) {
        // ---------------- classification: 20 classes of the focal-BCE ----------------
        const int chq = role - 4;                       // 0..3 -> classes [chq*20, chq*20+20)
        if (t < NT) {
            const float* p; int HW, W, off, gbase; float stride;
            scale_map(t, p0, p1, p2, p, HW, W, stride, off, gbase);

            const int4 m4 = *(const int4*)(matched + (size_t)b * NA + gbase + off);
            const int mm[4] = {m4.x, m4.y, m4.z, m4.w};
            int lbl[4];
            #pragma unroll
            for (int j = 0; j < 4; ++j)
                lbl[j] = (mm[j] >= 0) ? gt_labels[b * MAX_GT + mm[j]] : -1;   // -1 never matches

            const float* pcls = p + (size_t)(b * 144 + 4 * BINS + chq * 20) * (size_t)HW + (size_t)off;

            #pragma unroll 4
            for (int cc = 0; cc < 20; ++cc) {
                const int c = chq * 20 + cc;
                float4 q = *(const float4*)(pcls + (size_t)cc * HW);
                const float s4[4] = {q.x, q.y, q.z, q.w};
                #pragma unroll
                for (int j = 0; j < 4; ++j) {
                    float s  = s4[j];
                    float tt = (c == lbl[j]) ? 1.f : 0.f;
                    float e   = __expf(-fabsf(s));
                    float inv = 1.f / (1.f + e);
                    float prob = (s >= 0.f) ? inv : e * inv;     // sigmoid
                    float ce  = fmaxf(s, 0.f) - s * tt + __logf(1.f + e);
                    float p_t = prob * tt + (1.f - prob) * (1.f - tt);
                    float alpha_t = tt * ALPHA_C + (1.f - tt) * (1.f - ALPHA_C);
                    float om = 1.f - p_t;
                    part += alpha_t * om * om * ce;
                }
            }
        }
        block_reduce_atomic(part, &acc[0]);
    } else {
        // ---------------- DFL side k: softmax over 16 bins, write pdist plane ----------------
        const int k = role;
        if (t < NT) {
            const float* p; int HW, W, off, gbase; float stride;
            scale_map(t, p0, p1, p2, p, HW, W, stride, off, gbase);
            const float inv_s = 1.f / stride;

            const int h  = off / W;
            const int w0 = off - h * W;
            const float cy = ((float)h + 0.5f) * stride;

            const int4 m4 = *(const int4*)(matched + (size_t)b * NA + gbase + off);
            const int mm[4] = {m4.x, m4.y, m4.z, m4.w};

            float tdv[4]; bool pos[4];
            #pragma unroll
            for (int j = 0; j < 4; ++j) {
                pos[j] = (mm[j] >= 0);
                int idx = pos[j] ? mm[j] : 0;
                float4 tb = *(const float4*)(gt_bboxes + ((size_t)b * MAX_GT + idx) * 4);
                float cx = ((float)(w0 + j) + 0.5f) * stride;
                float d;
                if      (k == 0) d = cx   - tb.x;   // block-uniform branch
                else if (k == 1) d = cy   - tb.y;
                else if (k == 2) d = tb.z - cx;
                else             d = tb.w - cy;
                tdv[j] = fmaxf(d, 0.f) * inv_s;
            }

            const float* pc = p + (size_t)(b * 144 + k * BINS) * (size_t)HW + (size_t)off;
            float v[BINS][4];
            #pragma unroll
            for (int i = 0; i < BINS; ++i) {
                float4 q = *(const float4*)(pc + (size_t)i * HW);
                v[i][0] = q.x; v[i][1] = q.y; v[i][2] = q.z; v[i][3] = q.w;
            }

            float pd[4];
            #pragma unroll
            for (int j = 0; j < 4; ++j) {
                float tval = fminf(tdv[j], (float)(BINS - 1) - 1e-6f);
                int   lo = (int)floorf(tval);        // 0..14 -> hi = lo+1 always valid
                float fr = tval - (float)lo;

                float mx = v[0][j];
                #pragma unroll
                for (int i = 1; i < BINS; ++i) mx = fmaxf(mx, v[i][j]);

                float se = 0.f, we = 0.f, vlo = 0.f, vhi = 0.f;
                #pragma unroll
                for (int i = 0; i < BINS; ++i) {
                    float e = __expf(v[i][j] - mx);
                    se += e;
                    we += (float)i * e;
                    vlo = (i == lo)     ? v[i][j] : vlo;
                    vhi = (i == lo + 1) ? v[i][j] : vhi;
                }
                pd[j] = (we / se) * stride;
                if (pos[j]) {
                    float lse = mx + __logf(se);
                    part += -((1.f - fr) * (vlo - lse) + fr * (vhi - lse));
                }
            }
            float4 st = {pd[0], pd[1], pd[2], pd[3]};
            *(float4*)(pdist + (size_t)k * AN + (size_t)b * NA + gbase + off) = st;
        }
        block_reduce_atomic(part, &acc[2]);
    }
}

// grid (9, BATCH), block 256: IoU + positive count from pdist planes
__global__ __launch_bounds__(256) void yolo_iou(
    const float* __restrict__ gt_bboxes, const int* __restrict__ matched,
    const float* __restrict__ pdist, double* __restrict__ acc)
{
    const int t = blockIdx.x * 256 + threadIdx.x;
    const int b = blockIdx.y;

    float iou_acc = 0.f, cnt = 0.f;

    if (t < NT) {
        const float* dummy; int HW, W, off, gbase; float stride;
        scale_map(t, dummy, dummy, dummy, dummy, HW, W, stride, off, gbase);

        const int h  = off / W;
        const int w0 = off - h * W;
        const float cy = ((float)h + 0.5f) * stride;

        const int4 m4 = *(const int4*)(matched + (size_t)b * NA + gbase + off);
        const int mm[4] = {m4.x, m4.y, m4.z, m4.w};

        float pdj[4][4];   // [k][j]
        #pragma unroll
        for (int k = 0; k < 4; ++k) {
            float4 q = *(const float4*)(pdist + (size_t)k * AN + (size_t)b * NA + gbase + off);
            pdj[k][0] = q.x; pdj[k][1] = q.y; pdj[k][2] = q.z; pdj[k][3] = q.w;
        }

        #pragma unroll
        for (int j = 0; j < 4; ++j) {
            if (mm[j] >= 0) {
                float4 tb = *(const float4*)(gt_bboxes + ((size_t)b * MAX_GT + mm[j]) * 4);
                float cx = ((float)(w0 + j) + 0.5f) * stride;
                float px1 = cx - pdj[0][j], py1 = cy - pdj[1][j];
                float px2 = cx + pdj[2][j], py2 = cy + pdj[3][j];
                float ix1 = fmaxf(px1, tb.x), iy1 = fmaxf(py1, tb.y);
                float ix2 = fminf(px2, tb.z), iy2 = fminf(py2, tb.w);
                float inter  = fmaxf(ix2 - ix1, 0.f) * fmaxf(iy2 - iy1, 0.f);
                float area_p = fmaxf(px2 - px1, 0.f) * fmaxf(py2 - py1, 0.f);
                float area_t = fmaxf(tb.z - tb.x, 0.f) * fmaxf(tb.w - tb.y, 0.f);
                float iou = inter / (area_p + area_t - inter + EPS_F);
                iou_acc += 1.f - iou;
                cnt += 1.f;
            }
        }
    }
    block_reduce_atomic(iou_acc, &acc[1]);
    block_reduce_atomic(cnt,     &acc[3]);
}

// ---------------- fallback: known-good fused kernel (round 1) ----------------
__global__ __launch_bounds__(256) void yolo_loss_fused(
    const float* __restrict__ p0, const float* __restrict__ p1, const float* __restrict__ p2,
    const float* __restrict__ gt_bboxes, const int* __restrict__ gt_labels,
    const int* __restrict__ matched, double* __restrict__ acc)
{
    const int a = blockIdx.x * blockDim.x + threadIdx.x;
    const int b = blockIdx.y;
    float cls_acc = 0.f, iou_acc = 0.f, dfl_acc = 0.f;
    int pos_cnt = 0;
    if (a < NA) {
        const float* p; int HW, W; float stride; int off;
        if (a < 6400)      { p = p0; HW = 6400; W = 80; stride = 8.f;  off = a; }
        else if (a < 8000) { p = p1; HW = 1600; W = 40; stride = 16.f; off = a - 6400; }
        else               { p = p2; HW = 400;  W = 20; stride = 32.f; off = a - 8000; }
        const int h = off / W, w = off - h * W;
        const float cx = ((float)w + 0.5f) * stride, cy = ((float)h + 0.5f) * stride;
        const float* pb = p + ((size_t)b * 144) * (size_t)HW + (size_t)off;
        const int m = matched[(size_t)b * NA + a];
        const bool pos = (m >= 0);
        const int idx = pos ? m : 0;
        const int lbl = gt_labels[b * MAX_GT + idx];
        const float* tbp = gt_bboxes + ((size_t)b * MAX_GT + idx) * 4;
        const float tx1 = tbp[0], ty1 = tbp[1], tx2 = tbp[2], ty2 = tbp[3];
        float tdist[4] = {fmaxf(cx - tx1, 0.f) / stride, fmaxf(cy - ty1, 0.f) / stride,
                          fmaxf(tx2 - cx, 0.f) / stride, fmaxf(ty2 - cy, 0.f) / stride};
        float pdv[4]; float dfl_sum = 0.f;
        #pragma unroll
        for (int k = 0; k < 4; ++k) {
            float tv = fminf(tdist[k], (float)(BINS - 1) - 1e-6f);
            int lo = (int)floorf(tv);
            float fr = tv - (float)lo;
            const float* pc = pb + (size_t)(k * BINS) * HW;
            float v[BINS];
            #pragma unroll
            for (int i = 0; i < BINS; ++i) v[i] = pc[(size_t)i * HW];
            float mx = v[0];
            #pragma unroll
            for (int i = 1; i < BINS; ++i) mx = fmaxf(mx, v[i]);
            float se = 0.f, we = 0.f, vlo = 0.f, vhi = 0.f;
            #pragma unroll
            for (int i = 0; i < BINS; ++i) {
                float e = __expf(v[i] - mx);
                se += e; we += (float)i * e;
                vlo = (i == lo) ? v[i] : vlo;
                vhi = (i == lo + 1) ? v[i] : vhi;
            }
            pdv[k] = (we / se) * stride;
            if (pos) { float lse = mx + __logf(se); dfl_sum += -((1.f - fr) * (vlo - lse) + fr * (vhi - lse)); }
        }
        const float* pcls = pb + (size_t)(4 * BINS) * HW;
        #pragma unroll 4
        for (int c = 0; c < NCLS; ++c) {
            float s = pcls[(size_t)c * HW];
            float tt = (pos && c == lbl) ? 1.f : 0.f;
            float e = __expf(-fabsf(s));
            float inv = 1.f / (1.f + e);
            float prob = (s >= 0.f) ? inv : e * inv;
            float ce = fmaxf(s, 0.f) - s * tt + __logf(1.f + e);
            float p_t = prob * tt + (1.f - prob) * (1.f - tt);
            float alpha_t = tt * ALPHA_C + (1.f - tt) * (1.f - ALPHA_C);
            float om = 1.f - p_t;
            cls_acc += alpha_t * om * om * ce;
        }
        if (pos) {
            float px1 = cx - pdv[0], py1 = cy - pdv[1], px2 = cx + pdv[2], py2 = cy + pdv[3];
            float ix1 = fmaxf(px1, tx1), iy1 = fmaxf(py1, ty1);
            float ix2 = fminf(px2, tx2), iy2 = fminf(py2, ty2);
            float inter  = fmaxf(ix2 - ix1, 0.f) * fmaxf(iy2 - iy1, 0.f);
            float area_p = fmaxf(px2 - px1, 0.f) * fmaxf(py2 - py1, 0.f);
            float area_t = fmaxf(tx2 - tx1, 0.f) * fmaxf(ty2 - ty1, 0.f);
            float iou = inter / (area_p + area_t - inter + EPS_F);
            iou_acc = 1.f - iou; dfl_acc = dfl_sum; pos_cnt = 1;
        }
    }
    #pragma unroll
    for (int o = 32; o > 0; o >>= 1) {
        cls_acc += __shfl_down(cls_acc, o);
        iou_acc += __shfl_down(iou_acc, o);
        dfl_acc += __shfl_down(dfl_acc, o);
        pos_cnt += __shfl_down(pos_cnt, o);
    }
    __shared__ float sc[4], si[4], sd[4]; __shared__ int sn[4];
    const int wave = threadIdx.x >> 6, lane = threadIdx.x & 63;
    if (lane == 0) { sc[wave] = cls_acc; si[wave] = iou_acc; sd[wave] = dfl_acc; sn[wave] = pos_cnt; }
    __syncthreads();
    if (threadIdx.x == 0) {
        atomicAdd(&acc[0], (double)(sc[0]+sc[1]+sc[2]+sc[3]));
        atomicAdd(&acc[1], (double)(si[0]+si[1]+si[2]+si[3]));
        atomicAdd(&acc[2], (double)(sd[0]+sd[1]+sd[2]+sd[3]));
        atomicAdd(&acc[3], (double)(sn[0]+sn[1]+sn[2]+sn[3]));
    }
}

__global__ void yolo_loss_finalize(const double* __restrict__ acc, float* __restrict__ out)
{
    double np = acc[3] < 1.0 ? 1.0 : acc[3];
    double total = W_CLS * acc[0] / np + W_IOU * acc[1] / np + W_DFL * acc[2] / (np * 4.0);
    out[0] = (float)total;
}

extern "C" void kernel_launch(void* const* d_in, const int* in_sizes, int n_in,
                              void* d_out, int out_size, void* d_ws, size_t ws_size,
                              hipStream_t stream)
{
    const float* p0        = (const float*)d_in[0];
    const float* p1        = (const float*)d_in[1];
    const float* p2        = (const float*)d_in[2];
    const float* gt_bboxes = (const float*)d_in[3];
    const int*   gt_labels = (const int*)d_in[4];
    const int*   matched   = (const int*)d_in[5];
    float*  out   = (float*)d_out;
    double* acc   = (double*)d_ws;
    float*  pdist = (float*)((char*)d_ws + 256);

    (void)hipMemsetAsync(acc, 0, 4 * sizeof(double), stream);

    const size_t need = 256 + (size_t)4 * AN * sizeof(float);   // ~4.3 MB
    if (ws_size >= need) {
        dim3 g1((NT + 255) / 256, 8, BATCH);    // 9 x 8 x 32
        yolo_dfl_cls<<<g1, 256, 0, stream>>>(p0, p1, p2, gt_bboxes, gt_labels, matched, pdist, acc);
        dim3 g2((NT + 255) / 256, BATCH);       // 9 x 32
        yolo_iou<<<g2, 256, 0, stream>>>(gt_bboxes, matched, pdist, acc);
    } else {
        dim3 g((NA + 255) / 256, BATCH);
        yolo_loss_fused<<<g, 256, 0, stream>>>(p0, p1, p2, gt_bboxes, gt_labels, matched, acc);
    }
    yolo_loss_finalize<<<1, 1, 0, stream>>>(acc, out);
}